// Round 3
// baseline (1029.618 us; speedup 1.0000x reference)
//
#include <hip/hip_runtime.h>
#include <stdint.h>

// MoE: T=8192 tokens, D=1024, E=8 experts, H=4096, top-2. fp32 IO, bf16 MFMA internal.
#define T_TOK 8192
#define D_DIM 1024
#define E_NUM 8
#define H_DIM 4096

#define BM 128
#define BN 128
#define BK 64
#define NSEG 8                           // expert segments (a token never repeats an expert)
#define MAX_ROWS2 17408                  // >= 2*T + 8*127, multiple of BM
#define MAX_MT2 (MAX_ROWS2/BM)           // 136
#define LCS 136                          // fc1 epilogue LDS tile stride (u16), 272B rows: 16B-aligned

typedef unsigned short u16;
typedef __attribute__((ext_vector_type(8))) short shortx8;
typedef __attribute__((ext_vector_type(4))) float floatx4;
typedef __attribute__((ext_vector_type(8))) unsigned short ushortx8;

typedef const __attribute__((address_space(1))) unsigned int g_uint;
typedef __attribute__((address_space(3))) unsigned int l_uint;

__device__ __forceinline__ u16 f2bf(float f) {
  union { float f; unsigned int u; } v; v.f = f;
  unsigned int r = v.u + 0x7FFFu + ((v.u >> 16) & 1u);  // RTNE
  return (u16)(r >> 16);
}
__device__ __forceinline__ void gld_lds16(const u16* g, u16* l) {
  __builtin_amdgcn_global_load_lds((g_uint*)g, (l_uint*)l, 16, 0, 0);
}
// tanh-approx GELU via sigmoid: gelu(v) ~= v * sigmoid(1.5957691216 v + 0.07135481627 v^3)
__device__ __forceinline__ float gelu_fast(float v) {
  float y = v * (1.5957691216f + 0.07135481627f * v * v);
  y = fminf(y, 30.f);                      // overflow guard
  float ey = __expf(y);
  return v * ey * __builtin_amdgcn_rcpf(1.f + ey);
}

// XCD-aware 1-D block decode: per-XCD stream iterates all NT ntiles of one mtile
// consecutively -> A-tile sharers co-resident on ONE XCD's L2 (dispatch is flat%8 rr).
// Requires cmc % 8 == 0 for the bijective form; falls back to plain decode otherwise.
__device__ __forceinline__ void decode_block(int flat, int NT, int cmc, int& ntile, int& mloc) {
  if ((cmc & 7) == 0) {
    int xcd = flat & 7, seq = flat >> 3;
    ntile = seq & (NT - 1);
    mloc = (seq / NT) * 8 + xcd;
  } else {
    ntile = flat & (NT - 1);
    mloc = flat / NT;
  }
}

// ---------------- init ------------------------------------------------------
__global__ __launch_bounds__(256) void init_kernel(int* counts, int* fills, int* row_token) {
  int i = blockIdx.x * 256 + threadIdx.x;
  if (i < MAX_ROWS2) row_token[i] = -1;
  if (blockIdx.x == 0 && threadIdx.x < NSEG) { counts[threadIdx.x] = 0; fills[threadIdx.x] = 0; }
}

// ---------------- zero out (float4), fallback only --------------------------
__global__ __launch_bounds__(256) void zero4_kernel(float4* out) {
  out[(size_t)blockIdx.x * 256 + threadIdx.x] = float4{0.f, 0.f, 0.f, 0.f};
}

// ------- gating (fused with x fp32->bf16 convert): one wave per token -------
__global__ __launch_bounds__(256) void gate_kernel(const float* __restrict__ X, const float* __restrict__ GW,
                                                   u16* __restrict__ XC,
                                                   int* __restrict__ tk_idx, float* __restrict__ tk_w,
                                                   int* __restrict__ counts) {
  const int lane = threadIdx.x & 63;
  const int t = blockIdx.x * 4 + (threadIdx.x >> 6);
  const float4* xr4 = (const float4*)(X + (size_t)t * D_DIM + lane * 16);
  const float4* gw4 = (const float4*)GW;
  float acc[E_NUM];
#pragma unroll
  for (int e = 0; e < E_NUM; e++) acc[e] = 0.f;
  ushortx8 o0, o1;
#pragma unroll
  for (int i4 = 0; i4 < 4; i4++) {
    float4 xv = xr4[i4];
#pragma unroll
    for (int c = 0; c < 4; c++) {
      float xs = (&xv.x)[c];
      int q = i4 * 4 + c;
      if (q < 8) o0[q] = f2bf(xs); else o1[q - 8] = f2bf(xs);
      int d = lane * 16 + q;
      float4 g0 = gw4[d * 2], g1 = gw4[d * 2 + 1];
      acc[0] += xs * g0.x; acc[1] += xs * g0.y; acc[2] += xs * g0.z; acc[3] += xs * g0.w;
      acc[4] += xs * g1.x; acc[5] += xs * g1.y; acc[6] += xs * g1.z; acc[7] += xs * g1.w;
    }
  }
  u16* xcb = XC + (size_t)t * D_DIM + lane * 16;
  *(ushortx8*)xcb = o0;
  *(ushortx8*)(xcb + 8) = o1;
#pragma unroll
  for (int e = 0; e < E_NUM; e++)
    for (int off = 32; off; off >>= 1) acc[e] += __shfl_xor(acc[e], off);
  if (lane == 0) {
    int i0 = 0; float v0 = acc[0];
#pragma unroll
    for (int e = 1; e < E_NUM; e++) if (acc[e] > v0) { v0 = acc[e]; i0 = e; }
    int i1 = -1; float v1 = -1e30f;
#pragma unroll
    for (int e = 0; e < E_NUM; e++) if (e != i0 && acc[e] > v1) { v1 = acc[e]; i1 = e; }
    float e1 = expf(v1 - v0);           // v1 <= v0, stable
    float inv = 1.f / (1.f + e1);
    tk_idx[t * 2] = i0; tk_idx[t * 2 + 1] = i1;
    tk_w[t * 2] = inv;  tk_w[t * 2 + 1] = e1 * inv;
    atomicAdd(&counts[i0], 1); atomicAdd(&counts[i1], 1);
  }
}

// ---------------- prefix over 8 expert segments, padded to BM ---------------
__global__ void prefix_kernel(const int* counts, int* seg) {
  if (threadIdx.x == 0 && blockIdx.x == 0) {
    int a = 0;
    for (int i = 0; i < NSEG; i++) { seg[i] = a; a += ((counts[i] + BM - 1) / BM) * BM; }
    seg[NSEG] = a;
  }
}

// ---------------- fill: scatter tokens into packed rows ---------------------
__global__ __launch_bounds__(256) void fill_kernel(const int* __restrict__ tk_idx, const float* __restrict__ tk_w,
                                                   const int* __restrict__ seg, int* __restrict__ fills,
                                                   int* __restrict__ row_token, float* __restrict__ row_weight,
                                                   int* __restrict__ row_of) {
  int t = blockIdx.x * 256 + threadIdx.x;
  if (t >= T_TOK) return;
#pragma unroll
  for (int s = 0; s < 2; s++) {
    int sidx = tk_idx[t * 2 + s];
    int pos = atomicAdd(&fills[sidx], 1);
    int r = seg[sidx] + pos;
    row_token[r] = t; row_weight[r] = tk_w[t * 2 + s];
    row_of[t * 2 + s] = r;
  }
}

// -------- weight convert+transpose fp32 [R][C] -> bf16 [C][R], 64x64 tiles --
__global__ __launch_bounds__(256) void transpose_kernel(const float* __restrict__ src, u16* __restrict__ dst,
                                                        int R, int C) {
  __shared__ u16 tile[64][68];
  const int tid = threadIdx.x;
  size_t off = (size_t)blockIdx.z * (size_t)R * C;
  int r0 = blockIdx.y * 64, c0 = blockIdx.x * 64;
  int rr = tid >> 4, cc = (tid & 15) * 4;
#pragma unroll
  for (int i = 0; i < 4; i++) {
    int r = rr + i * 16;
    float4 v = *(const float4*)&src[off + (size_t)(r0 + r) * C + c0 + cc];
    u16* tp = &tile[r][cc];
    tp[0] = f2bf(v.x); tp[1] = f2bf(v.y); tp[2] = f2bf(v.z); tp[3] = f2bf(v.w);
  }
  __syncthreads();
  int c = tid >> 3, rb = (tid & 7) * 8;
#pragma unroll
  for (int i = 0; i < 2; i++) {
    int cx = c + i * 32;
    ushortx8 o;
#pragma unroll
    for (int q = 0; q < 8; q++) o[q] = tile[rb + q][cx];
    *(ushortx8*)&dst[off + (size_t)(c0 + cx) * R + r0 + rb] = o;
  }
}

// ---------------- fc1: Hbuf(bf16) = gelu(Xc @ W1t[e] + b1) ------------------
__global__ __launch_bounds__(256, 4) void fc1_kernel(const u16* __restrict__ XC, const u16* __restrict__ W1T,
                                                     const float* __restrict__ B1, u16* __restrict__ Hbuf,
                                                     const int* __restrict__ row_token, const int* __restrict__ seg,
                                                     int mtile0, int cmc, int e_filter) {
  int ntile, mloc;
  decode_block(blockIdx.x, H_DIM / BN, cmc, ntile, mloc);
  const int mtile = mtile0 + mloc;
  const int row0 = mtile * BM;
  if (row0 >= seg[NSEG]) return;
  int sidx = 0;
#pragma unroll
  for (int i = 1; i < NSEG; i++) if (row0 >= seg[i]) sidx = i;
  const int e = sidx;
  if (e_filter >= 0 && e != e_filter) return;
  const size_t ebase = (e_filter >= 0) ? 0 : (size_t)e * H_DIM;
  const u16* Bbase = W1T + (ebase + (size_t)ntile * BN) * D_DIM;

  __shared__ u16 lds_u16[BM * LCS];       // 34816B: k-loop uses [0,16384); epilogue full
  u16* lA = lds_u16;
  u16* lB = lds_u16 + BM * BK;
  const int tid = threadIdx.x;
  const int sub = tid >> 3, acol = (tid & 7) * 8;
  unsigned int offA[4], offB[4];          // element offsets off SGPR bases
#pragma unroll
  for (int r = 0; r < 4; r++) {
    int arow = r * 32 + sub;
    int tok = row_token[row0 + arow]; if (tok < 0) tok = 0;   // pad rows: dummy token, discarded
    offA[r] = (unsigned int)tok * D_DIM + acol;
    offB[r] = (unsigned int)arow * D_DIM + acol;
  }
  const int lane = tid & 63;
  const int mq = (tid >> 7) & 1, nq = (tid >> 6) & 1;
  const int lrow = lane & 15, quad = lane >> 4;
  floatx4 acc[4][4];
#pragma unroll
  for (int i = 0; i < 4; i++)
#pragma unroll
    for (int j = 0; j < 4; j++)
#pragma unroll
      for (int r = 0; r < 4; r++) acc[i][j][r] = 0.f;

  for (int k0 = 0; k0 < D_DIM; k0 += BK) {
#pragma unroll
    for (int r = 0; r < 4; r++) gld_lds16(XC + offA[r] + k0, &lA[(r * 256 + tid) * 8]);
#pragma unroll
    for (int r = 0; r < 4; r++) gld_lds16(Bbase + offB[r] + k0, &lB[(r * 256 + tid) * 8]);
    __syncthreads();
#pragma unroll
    for (int kk = 0; kk < 2; kk++) {
      shortx8 af[4], bfr[4];
#pragma unroll
      for (int i = 0; i < 4; i++) af[i]  = *(const shortx8*)&lA[(mq * 64 + i * 16 + lrow) * BK + kk * 32 + quad * 8];
#pragma unroll
      for (int i = 0; i < 4; i++) bfr[i] = *(const shortx8*)&lB[(nq * 64 + i * 16 + lrow) * BK + kk * 32 + quad * 8];
#pragma unroll
      for (int i = 0; i < 4; i++)
#pragma unroll
        for (int j = 0; j < 4; j++)
          acc[i][j] = __builtin_amdgcn_mfma_f32_16x16x32_bf16(af[i], bfr[j], acc[i][j], 0, 0, 0);
    }
    __syncthreads();
  }
  // epilogue: gelu -> LDS bounce -> coalesced 16B stores (fixes 2B-store write amp)
#pragma unroll
  for (int j = 0; j < 4; j++) {
    float bv = B1[(size_t)e * H_DIM + ntile * BN + nq * 64 + j * 16 + lrow];
    int col = nq * 64 + j * 16 + lrow;
#pragma unroll
    for (int i = 0; i < 4; i++) {
      int row = mq * 64 + i * 16 + quad * 4;
#pragma unroll
      for (int rr = 0; rr < 4; rr++) {
        float v = acc[i][j][rr] + bv;
        lds_u16[(row + rr) * LCS + col] = f2bf(gelu_fast(v));
      }
    }
  }
  __syncthreads();
  {
    const int r = tid >> 1, c0 = (tid & 1) * 64;
    size_t gbase = (size_t)(mloc * BM + r) * H_DIM + (size_t)ntile * BN + c0;
#pragma unroll
    for (int q = 0; q < 8; q++)
      *(ushortx8*)&Hbuf[gbase + q * 8] = *(const ushortx8*)&lds_u16[r * LCS + c0 + q * 8];
  }
}

// ---------------- fc2: outbuf[row][D] = (Hbuf @ W2t[e] + b2) * wgt ----------
__global__ __launch_bounds__(256, 4) void fc2_kernel(const u16* __restrict__ Hbuf, const u16* __restrict__ W2T,
                                                     const float* __restrict__ B2, float* __restrict__ outbuf,
                                                     const int* __restrict__ row_token, const float* __restrict__ row_weight,
                                                     const int* __restrict__ seg,
                                                     int mtile0, int cmc, int e_filter) {
  int ntile, mloc;
  decode_block(blockIdx.x, D_DIM / BN, cmc, ntile, mloc);
  const int mtile = mtile0 + mloc;
  const int row0 = mtile * BM;
  if (row0 >= seg[NSEG]) return;
  int sidx = 0;
#pragma unroll
  for (int i = 1; i < NSEG; i++) if (row0 >= seg[i]) sidx = i;
  const int e = sidx;
  if (e_filter >= 0 && e != e_filter) return;
  const size_t ebase = (e_filter >= 0) ? 0 : (size_t)e * D_DIM;
  const u16* Bbase = W2T + (ebase + (size_t)ntile * BN) * H_DIM;

  __shared__ u16 lA[BM * BK];
  __shared__ u16 lB[BN * BK];
  const int tid = threadIdx.x;
  const int sub = tid >> 3, acol = (tid & 7) * 8;
  unsigned int offA[4], offB[4];
#pragma unroll
  for (int r = 0; r < 4; r++) {
    int arow = r * 32 + sub;
    offA[r] = (unsigned int)(mloc * BM + arow) * H_DIM + acol;
    offB[r] = (unsigned int)arow * H_DIM + acol;
  }
  const int lane = tid & 63;
  const int mq = (tid >> 7) & 1, nq = (tid >> 6) & 1;
  const int lrow = lane & 15, quad = lane >> 4;
  floatx4 acc[4][4];
#pragma unroll
  for (int i = 0; i < 4; i++)
#pragma unroll
    for (int j = 0; j < 4; j++)
#pragma unroll
      for (int r = 0; r < 4; r++) acc[i][j][r] = 0.f;

  for (int k0 = 0; k0 < H_DIM; k0 += BK) {
#pragma unroll
    for (int r = 0; r < 4; r++) gld_lds16(Hbuf + offA[r] + k0, &lA[(r * 256 + tid) * 8]);
#pragma unroll
    for (int r = 0; r < 4; r++) gld_lds16(Bbase + offB[r] + k0, &lB[(r * 256 + tid) * 8]);
    __syncthreads();
#pragma unroll
    for (int kk = 0; kk < 2; kk++) {
      shortx8 af[4], bfr[4];
#pragma unroll
      for (int i = 0; i < 4; i++) af[i]  = *(const shortx8*)&lA[(mq * 64 + i * 16 + lrow) * BK + kk * 32 + quad * 8];
#pragma unroll
      for (int i = 0; i < 4; i++) bfr[i] = *(const shortx8*)&lB[(nq * 64 + i * 16 + lrow) * BK + kk * 32 + quad * 8];
#pragma unroll
      for (int i = 0; i < 4; i++)
#pragma unroll
        for (int j = 0; j < 4; j++)
          acc[i][j] = __builtin_amdgcn_mfma_f32_16x16x32_bf16(af[i], bfr[j], acc[i][j], 0, 0, 0);
    }
    __syncthreads();
  }
  // epilogue: +b2, scale by gate weight, single plain store per element (64B sectors)
#pragma unroll
  for (int i = 0; i < 4; i++)
#pragma unroll
    for (int rr = 0; rr < 4; rr++) {
      int gr = row0 + mq * 64 + i * 16 + quad * 4 + rr;
      int tok = row_token[gr];
      if (tok >= 0) {
        float wgt = row_weight[gr];
        float* obase = outbuf + (size_t)gr * D_DIM + (size_t)ntile * BN + nq * 64 + lrow;
#pragma unroll
        for (int j = 0; j < 4; j++) {
          float bv = B2[(size_t)e * D_DIM + ntile * BN + nq * 64 + j * 16 + lrow];
          obase[j * 16] = (acc[i][j][rr] + bv) * wgt;
        }
      }
    }
}

// ---------------- combine: out[t] = outbuf[r0] + outbuf[r1] -----------------
__global__ __launch_bounds__(256) void combine_kernel(const float* __restrict__ outbuf, const int* __restrict__ row_of,
                                                      float* __restrict__ out) {
  int t = blockIdx.x;
  int d = threadIdx.x * 4;
  int r0 = row_of[t * 2], r1 = row_of[t * 2 + 1];
  float4 a = *(const float4*)&outbuf[(size_t)r0 * D_DIM + d];
  float4 b = *(const float4*)&outbuf[(size_t)r1 * D_DIM + d];
  *(float4*)&out[(size_t)t * D_DIM + d] = float4{a.x + b.x, a.y + b.y, a.z + b.z, a.w + b.w};
}

extern "C" void kernel_launch(void* const* d_in, const int* in_sizes, int n_in,
                              void* d_out, int out_size, void* d_ws, size_t ws_size,
                              hipStream_t stream) {
  const float* x  = (const float*)d_in[0];   // [T][D] fp32
  const float* gw = (const float*)d_in[1];   // [D][E]
  const float* w1 = (const float*)d_in[2];   // [E][D][H]
  const float* b1 = (const float*)d_in[3];   // [E][H]
  const float* w2 = (const float*)d_in[4];   // [E][H][D]
  const float* b2 = (const float*)d_in[5];   // [E][D]
  float* out = (float*)d_out;

  char* p = (char*)d_ws;
  auto alloc = [&](size_t n) { char* q = p; p += (n + 255) & ~(size_t)255; return q; };
  int*   counts     = (int*)alloc(NSEG * 4);
  int*   fills      = (int*)alloc(NSEG * 4);
  int*   seg        = (int*)alloc((NSEG + 1) * 4);
  int*   tk_idx     = (int*)alloc((size_t)T_TOK * 2 * 4);
  float* tk_w       = (float*)alloc((size_t)T_TOK * 2 * 4);
  int*   row_token  = (int*)alloc((size_t)MAX_ROWS2 * 4);
  float* row_weight = (float*)alloc((size_t)MAX_ROWS2 * 4);
  int*   row_of     = (int*)alloc((size_t)T_TOK * 2 * 4);
  u16*   xc         = (u16*)alloc((size_t)T_TOK * D_DIM * 2);       // 16.8 MB bf16 x
  float* outbuf     = (float*)alloc((size_t)MAX_ROWS2 * D_DIM * 4); // 71.3 MB fp32 per-row out
  size_t meta = (size_t)(p - (char*)d_ws);

  const size_t Wfull = (size_t)E_NUM * H_DIM * D_DIM * 2;   // 67.1 MB bf16
  const size_t Wone  = (size_t)H_DIM * D_DIM * 2;           //  8.4 MB bf16
  auto hbytes = [](int n) { int cmx = (MAX_MT2 + n - 1) / n; return (size_t)cmx * BM * H_DIM * 2; };

  // mode 0: separate W1T+W2T, transposes hoisted; mode 1: shared W, transposes per chunk;
  // mode 2: per-expert W; mode 3: ws too small.
  int mode = 3, N = 1;
  {
    const int cand[6] = {1, 2, 4, 8, 16, 32};
    for (int ci = 0; ci < 6 && mode == 3; ci++)
      if (meta + 2 * Wfull + hbytes(cand[ci]) <= ws_size) { mode = 0; N = cand[ci]; }
    for (int ci = 0; ci < 6 && mode == 3; ci++)
      if (meta + Wfull + hbytes(cand[ci]) <= ws_size) { mode = 1; N = cand[ci]; }
    for (int ci = 0; ci < 6 && mode == 3; ci++)
      if (meta + Wone + hbytes(cand[ci]) <= ws_size) { mode = 2; N = cand[ci]; }
  }

  if (mode == 3) {  // ws too small for any tier: defined output, diagnostic fail
    zero4_kernel<<<(int)(((size_t)T_TOK * D_DIM) / 1024), 256, 0, stream>>>((float4*)out);
    return;
  }

  u16 *W1T, *W2T;
  if (mode == 0) { W1T = (u16*)alloc(Wfull); W2T = (u16*)alloc(Wfull); }
  else           { W1T = W2T = (u16*)alloc(mode == 1 ? Wfull : Wone); }
  u16* Hbuf = (u16*)alloc(hbytes(N));
  const int cm = (MAX_MT2 + N - 1) / N;

  init_kernel<<<(MAX_ROWS2 + 255) / 256, 256, 0, stream>>>(counts, fills, row_token);
  gate_kernel<<<T_TOK / 4, 256, 0, stream>>>(x, gw, xc, tk_idx, tk_w, counts);
  prefix_kernel<<<1, 64, 0, stream>>>(counts, seg);
  fill_kernel<<<T_TOK / 256, 256, 0, stream>>>(tk_idx, tk_w, seg, fills, row_token, row_weight, row_of);

  if (mode == 0) {
    transpose_kernel<<<dim3(H_DIM / 64, D_DIM / 64, E_NUM), 256, 0, stream>>>(w1, W1T, D_DIM, H_DIM);
    transpose_kernel<<<dim3(D_DIM / 64, H_DIM / 64, E_NUM), 256, 0, stream>>>(w2, W2T, H_DIM, D_DIM);
  }

  for (int c = 0; c < N; ++c) {
    int mtile0 = c * cm;
    int cmc = MAX_MT2 - mtile0; if (cmc > cm) cmc = cm; if (cmc <= 0) break;
    if (mode == 0) {
      fc1_kernel<<<cmc * (H_DIM / BN), 256, 0, stream>>>(xc, W1T, b1, Hbuf, row_token, seg, mtile0, cmc, -1);
      fc2_kernel<<<cmc * (D_DIM / BN), 256, 0, stream>>>(Hbuf, W2T, b2, outbuf, row_token, row_weight, seg, mtile0, cmc, -1);
    } else if (mode == 1) {
      transpose_kernel<<<dim3(H_DIM / 64, D_DIM / 64, E_NUM), 256, 0, stream>>>(w1, W1T, D_DIM, H_DIM);
      fc1_kernel<<<cmc * (H_DIM / BN), 256, 0, stream>>>(xc, W1T, b1, Hbuf, row_token, seg, mtile0, cmc, -1);
      transpose_kernel<<<dim3(D_DIM / 64, H_DIM / 64, E_NUM), 256, 0, stream>>>(w2, W2T, H_DIM, D_DIM);
      fc2_kernel<<<cmc * (D_DIM / BN), 256, 0, stream>>>(Hbuf, W2T, b2, outbuf, row_token, row_weight, seg, mtile0, cmc, -1);
    } else {
      for (int e = 0; e < E_NUM; e++) {
        transpose_kernel<<<dim3(H_DIM / 64, D_DIM / 64, 1), 256, 0, stream>>>(w1 + (size_t)e * D_DIM * H_DIM, W1T, D_DIM, H_DIM);
        fc1_kernel<<<cmc * (H_DIM / BN), 256, 0, stream>>>(xc, W1T, b1, Hbuf, row_token, seg, mtile0, cmc, e);
      }
      for (int e = 0; e < E_NUM; e++) {
        transpose_kernel<<<dim3(D_DIM / 64, H_DIM / 64, 1), 256, 0, stream>>>(w2 + (size_t)e * H_DIM * D_DIM, W2T, H_DIM, D_DIM);
        fc2_kernel<<<cmc * (D_DIM / BN), 256, 0, stream>>>(Hbuf, W2T, b2, outbuf, row_token, row_weight, seg, mtile0, cmc, e);
      }
    }
  }
  combine_kernel<<<T_TOK, 256, 0, stream>>>(outbuf, row_of, out);
}

// Round 4
// 981.493 us; speedup vs baseline: 1.0490x; 1.0490x over previous
//
#include <hip/hip_runtime.h>
#include <stdint.h>

// MoE: T=8192 tokens, D=1024, E=8 experts, H=4096, top-2. fp32 IO, bf16 MFMA internal.
#define T_TOK 8192
#define D_DIM 1024
#define E_NUM 8
#define H_DIM 4096

#define BM 128
#define BN 128
#define BK 64
#define NSEG 8                           // expert segments (a token never repeats an expert)
#define MAX_ROWS2 17408                  // >= 2*T + 8*127, multiple of BM
#define MAX_MT2 (MAX_ROWS2/BM)           // 136
#define LCS 136                          // fc1 epilogue LDS tile stride (u16), 272B rows: 16B-aligned

typedef unsigned short u16;
typedef __attribute__((ext_vector_type(8))) short shortx8;
typedef __attribute__((ext_vector_type(4))) float floatx4;
typedef __attribute__((ext_vector_type(8))) unsigned short ushortx8;

typedef const __attribute__((address_space(1))) unsigned int g_uint;
typedef __attribute__((address_space(3))) unsigned int l_uint;

__device__ __forceinline__ u16 f2bf(float f) {
  union { float f; unsigned int u; } v; v.f = f;
  unsigned int r = v.u + 0x7FFFu + ((v.u >> 16) & 1u);  // RTNE
  return (u16)(r >> 16);
}
__device__ __forceinline__ void gld_lds16(const u16* g, u16* l) {
  __builtin_amdgcn_global_load_lds((g_uint*)g, (l_uint*)l, 16, 0, 0);
}
// tanh-approx GELU via sigmoid: gelu(v) ~= v * sigmoid(1.5957691216 v + 0.07135481627 v^3)
__device__ __forceinline__ float gelu_fast(float v) {
  float y = v * (1.5957691216f + 0.07135481627f * v * v);
  y = fminf(y, 30.f);                      // overflow guard
  float ey = __expf(y);
  return v * ey * __builtin_amdgcn_rcpf(1.f + ey);
}

// ---------------- init ------------------------------------------------------
__global__ __launch_bounds__(256) void init_kernel(int* counts, int* fills, int* row_token) {
  int i = blockIdx.x * 256 + threadIdx.x;
  if (i < MAX_ROWS2) row_token[i] = -1;
  if (blockIdx.x == 0 && threadIdx.x < NSEG) { counts[threadIdx.x] = 0; fills[threadIdx.x] = 0; }
}

// ---------------- zero out (float4), fallback only --------------------------
__global__ __launch_bounds__(256) void zero4_kernel(float4* out) {
  out[(size_t)blockIdx.x * 256 + threadIdx.x] = float4{0.f, 0.f, 0.f, 0.f};
}

// ------- gating (fused with x fp32->bf16 convert): one wave per token -------
__global__ __launch_bounds__(256) void gate_kernel(const float* __restrict__ X, const float* __restrict__ GW,
                                                   u16* __restrict__ XC,
                                                   int* __restrict__ tk_idx, float* __restrict__ tk_w,
                                                   int* __restrict__ counts) {
  const int lane = threadIdx.x & 63;
  const int t = blockIdx.x * 4 + (threadIdx.x >> 6);
  const float4* xr4 = (const float4*)(X + (size_t)t * D_DIM + lane * 16);
  const float4* gw4 = (const float4*)GW;
  float acc[E_NUM];
#pragma unroll
  for (int e = 0; e < E_NUM; e++) acc[e] = 0.f;
  ushortx8 o0, o1;
#pragma unroll
  for (int i4 = 0; i4 < 4; i4++) {
    float4 xv = xr4[i4];
#pragma unroll
    for (int c = 0; c < 4; c++) {
      float xs = (&xv.x)[c];
      int q = i4 * 4 + c;
      if (q < 8) o0[q] = f2bf(xs); else o1[q - 8] = f2bf(xs);
      int d = lane * 16 + q;
      float4 g0 = gw4[d * 2], g1 = gw4[d * 2 + 1];
      acc[0] += xs * g0.x; acc[1] += xs * g0.y; acc[2] += xs * g0.z; acc[3] += xs * g0.w;
      acc[4] += xs * g1.x; acc[5] += xs * g1.y; acc[6] += xs * g1.z; acc[7] += xs * g1.w;
    }
  }
  u16* xcb = XC + (size_t)t * D_DIM + lane * 16;
  *(ushortx8*)xcb = o0;
  *(ushortx8*)(xcb + 8) = o1;
#pragma unroll
  for (int e = 0; e < E_NUM; e++)
    for (int off = 32; off; off >>= 1) acc[e] += __shfl_xor(acc[e], off);
  if (lane == 0) {
    int i0 = 0; float v0 = acc[0];
#pragma unroll
    for (int e = 1; e < E_NUM; e++) if (acc[e] > v0) { v0 = acc[e]; i0 = e; }
    int i1 = -1; float v1 = -1e30f;
#pragma unroll
    for (int e = 0; e < E_NUM; e++) if (e != i0 && acc[e] > v1) { v1 = acc[e]; i1 = e; }
    float e1 = expf(v1 - v0);           // v1 <= v0, stable
    float inv = 1.f / (1.f + e1);
    tk_idx[t * 2] = i0; tk_idx[t * 2 + 1] = i1;
    tk_w[t * 2] = inv;  tk_w[t * 2 + 1] = e1 * inv;
    atomicAdd(&counts[i0], 1); atomicAdd(&counts[i1], 1);
  }
}

// ---------------- prefix over 8 expert segments, padded to BM ---------------
__global__ void prefix_kernel(const int* counts, int* seg) {
  if (threadIdx.x == 0 && blockIdx.x == 0) {
    int a = 0;
    for (int i = 0; i < NSEG; i++) { seg[i] = a; a += ((counts[i] + BM - 1) / BM) * BM; }
    seg[NSEG] = a;
  }
}

// ---------------- fill: scatter tokens into packed rows ---------------------
__global__ __launch_bounds__(256) void fill_kernel(const int* __restrict__ tk_idx, const float* __restrict__ tk_w,
                                                   const int* __restrict__ seg, int* __restrict__ fills,
                                                   int* __restrict__ row_token, float* __restrict__ row_weight,
                                                   int* __restrict__ row_of) {
  int t = blockIdx.x * 256 + threadIdx.x;
  if (t >= T_TOK) return;
#pragma unroll
  for (int s = 0; s < 2; s++) {
    int sidx = tk_idx[t * 2 + s];
    int pos = atomicAdd(&fills[sidx], 1);
    int r = seg[sidx] + pos;
    row_token[r] = t; row_weight[r] = tk_w[t * 2 + s];
    row_of[t * 2 + s] = r;
  }
}

// -------- weight convert+transpose fp32 [R][C] -> bf16 [C][R], 64x64 tiles --
// stride 70 u16: phase-2 column reads land ~2 lanes/bank (stride-68 was ~4-way)
__global__ __launch_bounds__(256) void transpose_kernel(const float* __restrict__ src, u16* __restrict__ dst,
                                                        int R, int C) {
  __shared__ u16 tile[64][70];
  const int tid = threadIdx.x;
  size_t off = (size_t)blockIdx.z * (size_t)R * C;
  int r0 = blockIdx.y * 64, c0 = blockIdx.x * 64;
  int rr = tid >> 4, cc = (tid & 15) * 4;
#pragma unroll
  for (int i = 0; i < 4; i++) {
    int r = rr + i * 16;
    float4 v = *(const float4*)&src[off + (size_t)(r0 + r) * C + c0 + cc];
    u16* tp = &tile[r][cc];
    tp[0] = f2bf(v.x); tp[1] = f2bf(v.y); tp[2] = f2bf(v.z); tp[3] = f2bf(v.w);
  }
  __syncthreads();
  int c = tid >> 3, rb = (tid & 7) * 8;
#pragma unroll
  for (int i = 0; i < 2; i++) {
    int cx = c + i * 32;
    ushortx8 o;
#pragma unroll
    for (int q = 0; q < 8; q++) o[q] = tile[rb + q][cx];
    *(ushortx8*)&dst[off + (size_t)(c0 + cx) * R + r0 + rb] = o;
  }
}

// ---------------- fc1: Hbuf(bf16) = gelu(Xc @ W1t[e] + b1) ------------------
// T2 XOR swizzle: LDS dest is linear (global_load_lds constraint); the SOURCE
// column-chunk is pre-swizzled (chunk ^ row&7) and the fragment read applies
// the same XOR -> 16-lane fragment reads cover all 8 chunk octets = 2 lanes/bank.
__global__ __launch_bounds__(256, 4) void fc1_kernel(const u16* __restrict__ XC, const u16* __restrict__ W1T,
                                                     const float* __restrict__ B1, u16* __restrict__ Hbuf,
                                                     const int* __restrict__ row_token, const int* __restrict__ seg,
                                                     int mtile0, int e_filter) {
  const int ntile = blockIdx.x, mloc = blockIdx.y;
  const int mtile = mtile0 + mloc;
  const int row0 = mtile * BM;
  if (row0 >= seg[NSEG]) return;
  int sidx = 0;
#pragma unroll
  for (int i = 1; i < NSEG; i++) if (row0 >= seg[i]) sidx = i;
  const int e = sidx;
  if (e_filter >= 0 && e != e_filter) return;
  const size_t ebase = (e_filter >= 0) ? 0 : (size_t)e * H_DIM;
  const u16* Bbase = W1T + (ebase + (size_t)ntile * BN) * D_DIM;

  __shared__ u16 lds_u16[BM * LCS];       // 34816B: k-loop uses [0,16384); epilogue full
  u16* lA = lds_u16;
  u16* lB = lds_u16 + BM * BK;
  const int tid = threadIdx.x;
  const int sub = tid >> 3;
  const int csw = (((tid & 7) ^ (sub & 7)) * 8);   // swizzled source chunk (bytes/2)
  unsigned int offA[4], offB[4];          // element offsets off SGPR bases
#pragma unroll
  for (int r = 0; r < 4; r++) {
    int arow = r * 32 + sub;
    int tok = row_token[row0 + arow]; if (tok < 0) tok = 0;   // pad rows: dummy token, discarded
    offA[r] = (unsigned int)tok * D_DIM + csw;
    offB[r] = (unsigned int)arow * D_DIM + csw;
  }
  const int lane = tid & 63;
  const int mq = (tid >> 7) & 1, nq = (tid >> 6) & 1;
  const int lrow = lane & 15, quad = lane >> 4;
  const int rsw = lrow & 7;               // read-side XOR (row&7; mq/i*16 are 0 mod 8)
  floatx4 acc[4][4];
#pragma unroll
  for (int i = 0; i < 4; i++)
#pragma unroll
    for (int j = 0; j < 4; j++)
#pragma unroll
      for (int r = 0; r < 4; r++) acc[i][j][r] = 0.f;

  for (int k0 = 0; k0 < D_DIM; k0 += BK) {
#pragma unroll
    for (int r = 0; r < 4; r++) gld_lds16(XC + offA[r] + k0, &lA[(r * 256 + tid) * 8]);
#pragma unroll
    for (int r = 0; r < 4; r++) gld_lds16(Bbase + offB[r] + k0, &lB[(r * 256 + tid) * 8]);
    __syncthreads();
#pragma unroll
    for (int kk = 0; kk < 2; kk++) {
      const int ch = ((kk * 4 + quad) ^ rsw) * 8;
      shortx8 af[4], bfr[4];
#pragma unroll
      for (int i = 0; i < 4; i++) af[i]  = *(const shortx8*)&lA[(mq * 64 + i * 16 + lrow) * BK + ch];
#pragma unroll
      for (int i = 0; i < 4; i++) bfr[i] = *(const shortx8*)&lB[(nq * 64 + i * 16 + lrow) * BK + ch];
#pragma unroll
      for (int i = 0; i < 4; i++)
#pragma unroll
        for (int j = 0; j < 4; j++)
          acc[i][j] = __builtin_amdgcn_mfma_f32_16x16x32_bf16(af[i], bfr[j], acc[i][j], 0, 0, 0);
    }
    __syncthreads();
  }
  // epilogue: gelu -> LDS bounce -> coalesced 16B stores (fixes 2B-store write amp)
#pragma unroll
  for (int j = 0; j < 4; j++) {
    float bv = B1[(size_t)e * H_DIM + ntile * BN + nq * 64 + j * 16 + lrow];
    int col = nq * 64 + j * 16 + lrow;
#pragma unroll
    for (int i = 0; i < 4; i++) {
      int row = mq * 64 + i * 16 + quad * 4;
#pragma unroll
      for (int rr = 0; rr < 4; rr++) {
        float v = acc[i][j][rr] + bv;
        lds_u16[(row + rr) * LCS + col] = f2bf(gelu_fast(v));
      }
    }
  }
  __syncthreads();
  {
    const int r = tid >> 1, c0 = (tid & 1) * 64;
    size_t gbase = (size_t)(mloc * BM + r) * H_DIM + (size_t)ntile * BN + c0;
#pragma unroll
    for (int q = 0; q < 8; q++)
      *(ushortx8*)&Hbuf[gbase + q * 8] = *(const ushortx8*)&lds_u16[r * LCS + c0 + q * 8];
  }
}

// ---------------- fc2: outbuf[row][D] = (Hbuf @ W2t[e] + b2) * wgt ----------
__global__ __launch_bounds__(256, 4) void fc2_kernel(const u16* __restrict__ Hbuf, const u16* __restrict__ W2T,
                                                     const float* __restrict__ B2, float* __restrict__ outbuf,
                                                     const int* __restrict__ row_token, const float* __restrict__ row_weight,
                                                     const int* __restrict__ seg,
                                                     int mtile0, int e_filter) {
  const int ntile = blockIdx.x, mloc = blockIdx.y;
  const int mtile = mtile0 + mloc;
  const int row0 = mtile * BM;
  if (row0 >= seg[NSEG]) return;
  int sidx = 0;
#pragma unroll
  for (int i = 1; i < NSEG; i++) if (row0 >= seg[i]) sidx = i;
  const int e = sidx;
  if (e_filter >= 0 && e != e_filter) return;
  const size_t ebase = (e_filter >= 0) ? 0 : (size_t)e * D_DIM;
  const u16* Bbase = W2T + (ebase + (size_t)ntile * BN) * H_DIM;

  __shared__ u16 lA[BM * BK];
  __shared__ u16 lB[BN * BK];
  const int tid = threadIdx.x;
  const int sub = tid >> 3;
  const int csw = (((tid & 7) ^ (sub & 7)) * 8);   // swizzled source chunk
  unsigned int offA[4], offB[4];
#pragma unroll
  for (int r = 0; r < 4; r++) {
    int arow = r * 32 + sub;
    offA[r] = (unsigned int)(mloc * BM + arow) * H_DIM + csw;
    offB[r] = (unsigned int)arow * H_DIM + csw;
  }
  const int lane = tid & 63;
  const int mq = (tid >> 7) & 1, nq = (tid >> 6) & 1;
  const int lrow = lane & 15, quad = lane >> 4;
  const int rsw = lrow & 7;
  floatx4 acc[4][4];
#pragma unroll
  for (int i = 0; i < 4; i++)
#pragma unroll
    for (int j = 0; j < 4; j++)
#pragma unroll
      for (int r = 0; r < 4; r++) acc[i][j][r] = 0.f;

  for (int k0 = 0; k0 < H_DIM; k0 += BK) {
#pragma unroll
    for (int r = 0; r < 4; r++) gld_lds16(Hbuf + offA[r] + k0, &lA[(r * 256 + tid) * 8]);
#pragma unroll
    for (int r = 0; r < 4; r++) gld_lds16(Bbase + offB[r] + k0, &lB[(r * 256 + tid) * 8]);
    __syncthreads();
#pragma unroll
    for (int kk = 0; kk < 2; kk++) {
      const int ch = ((kk * 4 + quad) ^ rsw) * 8;
      shortx8 af[4], bfr[4];
#pragma unroll
      for (int i = 0; i < 4; i++) af[i]  = *(const shortx8*)&lA[(mq * 64 + i * 16 + lrow) * BK + ch];
#pragma unroll
      for (int i = 0; i < 4; i++) bfr[i] = *(const shortx8*)&lB[(nq * 64 + i * 16 + lrow) * BK + ch];
#pragma unroll
      for (int i = 0; i < 4; i++)
#pragma unroll
        for (int j = 0; j < 4; j++)
          acc[i][j] = __builtin_amdgcn_mfma_f32_16x16x32_bf16(af[i], bfr[j], acc[i][j], 0, 0, 0);
    }
    __syncthreads();
  }
  // epilogue: +b2, scale by gate weight, single plain store per element (64B sectors)
#pragma unroll
  for (int i = 0; i < 4; i++)
#pragma unroll
    for (int rr = 0; rr < 4; rr++) {
      int gr = row0 + mq * 64 + i * 16 + quad * 4 + rr;
      int tok = row_token[gr];
      if (tok >= 0) {
        float wgt = row_weight[gr];
        float* obase = outbuf + (size_t)gr * D_DIM + (size_t)ntile * BN + nq * 64 + lrow;
#pragma unroll
        for (int j = 0; j < 4; j++) {
          float bv = B2[(size_t)e * D_DIM + ntile * BN + nq * 64 + j * 16 + lrow];
          obase[j * 16] = (acc[i][j][rr] + bv) * wgt;
        }
      }
    }
}

// ---------------- combine: out[t] = outbuf[r0] + outbuf[r1] -----------------
__global__ __launch_bounds__(256) void combine_kernel(const float* __restrict__ outbuf, const int* __restrict__ row_of,
                                                      float* __restrict__ out) {
  int t = blockIdx.x;
  int d = threadIdx.x * 4;
  int r0 = row_of[t * 2], r1 = row_of[t * 2 + 1];
  float4 a = *(const float4*)&outbuf[(size_t)r0 * D_DIM + d];
  float4 b = *(const float4*)&outbuf[(size_t)r1 * D_DIM + d];
  *(float4*)&out[(size_t)t * D_DIM + d] = float4{a.x + b.x, a.y + b.y, a.z + b.z, a.w + b.w};
}

extern "C" void kernel_launch(void* const* d_in, const int* in_sizes, int n_in,
                              void* d_out, int out_size, void* d_ws, size_t ws_size,
                              hipStream_t stream) {
  const float* x  = (const float*)d_in[0];   // [T][D] fp32
  const float* gw = (const float*)d_in[1];   // [D][E]
  const float* w1 = (const float*)d_in[2];   // [E][D][H]
  const float* b1 = (const float*)d_in[3];   // [E][H]
  const float* w2 = (const float*)d_in[4];   // [E][H][D]
  const float* b2 = (const float*)d_in[5];   // [E][D]
  float* out = (float*)d_out;

  char* p = (char*)d_ws;
  auto alloc = [&](size_t n) { char* q = p; p += (n + 255) & ~(size_t)255; return q; };
  int*   counts     = (int*)alloc(NSEG * 4);
  int*   fills      = (int*)alloc(NSEG * 4);
  int*   seg        = (int*)alloc((NSEG + 1) * 4);
  int*   tk_idx     = (int*)alloc((size_t)T_TOK * 2 * 4);
  float* tk_w       = (float*)alloc((size_t)T_TOK * 2 * 4);
  int*   row_token  = (int*)alloc((size_t)MAX_ROWS2 * 4);
  float* row_weight = (float*)alloc((size_t)MAX_ROWS2 * 4);
  int*   row_of     = (int*)alloc((size_t)T_TOK * 2 * 4);
  u16*   xc         = (u16*)alloc((size_t)T_TOK * D_DIM * 2);       // 16.8 MB bf16 x
  float* outbuf     = (float*)alloc((size_t)MAX_ROWS2 * D_DIM * 4); // 71.3 MB fp32 per-row out
  size_t meta = (size_t)(p - (char*)d_ws);

  const size_t Wfull = (size_t)E_NUM * H_DIM * D_DIM * 2;   // 67.1 MB bf16
  const size_t Wone  = (size_t)H_DIM * D_DIM * 2;           //  8.4 MB bf16
  auto hbytes = [](int n) { int cmx = (MAX_MT2 + n - 1) / n; return (size_t)cmx * BM * H_DIM * 2; };

  // mode 0: separate W1T+W2T, transposes hoisted; mode 1: shared W, transposes per chunk;
  // mode 2: per-expert W; mode 3: ws too small.
  int mode = 3, N = 1;
  {
    const int cand[6] = {1, 2, 4, 8, 16, 32};
    for (int ci = 0; ci < 6 && mode == 3; ci++)
      if (meta + 2 * Wfull + hbytes(cand[ci]) <= ws_size) { mode = 0; N = cand[ci]; }
    for (int ci = 0; ci < 6 && mode == 3; ci++)
      if (meta + Wfull + hbytes(cand[ci]) <= ws_size) { mode = 1; N = cand[ci]; }
    for (int ci = 0; ci < 6 && mode == 3; ci++)
      if (meta + Wone + hbytes(cand[ci]) <= ws_size) { mode = 2; N = cand[ci]; }
  }

  if (mode == 3) {  // ws too small for any tier: defined output, diagnostic fail
    zero4_kernel<<<(int)(((size_t)T_TOK * D_DIM) / 1024), 256, 0, stream>>>((float4*)out);
    return;
  }

  u16 *W1T, *W2T;
  if (mode == 0) { W1T = (u16*)alloc(Wfull); W2T = (u16*)alloc(Wfull); }
  else           { W1T = W2T = (u16*)alloc(mode == 1 ? Wfull : Wone); }
  u16* Hbuf = (u16*)alloc(hbytes(N));
  const int cm = (MAX_MT2 + N - 1) / N;

  init_kernel<<<(MAX_ROWS2 + 255) / 256, 256, 0, stream>>>(counts, fills, row_token);
  gate_kernel<<<T_TOK / 4, 256, 0, stream>>>(x, gw, xc, tk_idx, tk_w, counts);
  prefix_kernel<<<1, 64, 0, stream>>>(counts, seg);
  fill_kernel<<<T_TOK / 256, 256, 0, stream>>>(tk_idx, tk_w, seg, fills, row_token, row_weight, row_of);

  if (mode == 0) {
    transpose_kernel<<<dim3(H_DIM / 64, D_DIM / 64, E_NUM), 256, 0, stream>>>(w1, W1T, D_DIM, H_DIM);
    transpose_kernel<<<dim3(D_DIM / 64, H_DIM / 64, E_NUM), 256, 0, stream>>>(w2, W2T, H_DIM, D_DIM);
  }

  for (int c = 0; c < N; ++c) {
    int mtile0 = c * cm;
    int cmc = MAX_MT2 - mtile0; if (cmc > cm) cmc = cm; if (cmc <= 0) break;
    if (mode == 0) {
      fc1_kernel<<<dim3(H_DIM / BN, cmc), 256, 0, stream>>>(xc, W1T, b1, Hbuf, row_token, seg, mtile0, -1);
      fc2_kernel<<<dim3(D_DIM / BN, cmc), 256, 0, stream>>>(Hbuf, W2T, b2, outbuf, row_token, row_weight, seg, mtile0, -1);
    } else if (mode == 1) {
      transpose_kernel<<<dim3(H_DIM / 64, D_DIM / 64, E_NUM), 256, 0, stream>>>(w1, W1T, D_DIM, H_DIM);
      fc1_kernel<<<dim3(H_DIM / BN, cmc), 256, 0, stream>>>(xc, W1T, b1, Hbuf, row_token, seg, mtile0, -1);
      transpose_kernel<<<dim3(D_DIM / 64, H_DIM / 64, E_NUM), 256, 0, stream>>>(w2, W2T, H_DIM, D_DIM);
      fc2_kernel<<<dim3(D_DIM / BN, cmc), 256, 0, stream>>>(Hbuf, W2T, b2, outbuf, row_token, row_weight, seg, mtile0, -1);
    } else {
      for (int e = 0; e < E_NUM; e++) {
        transpose_kernel<<<dim3(H_DIM / 64, D_DIM / 64, 1), 256, 0, stream>>>(w1 + (size_t)e * D_DIM * H_DIM, W1T, D_DIM, H_DIM);
        fc1_kernel<<<dim3(H_DIM / BN, cmc), 256, 0, stream>>>(xc, W1T, b1, Hbuf, row_token, seg, mtile0, e);
      }
      for (int e = 0; e < E_NUM; e++) {
        transpose_kernel<<<dim3(D_DIM / 64, H_DIM / 64, 1), 256, 0, stream>>>(w2 + (size_t)e * H_DIM * D_DIM, W2T, H_DIM, D_DIM);
        fc2_kernel<<<dim3(D_DIM / BN, cmc), 256, 0, stream>>>(Hbuf, W2T, b2, outbuf, row_token, row_weight, seg, mtile0, e);
      }
    }
  }
  combine_kernel<<<T_TOK, 256, 0, stream>>>(outbuf, row_of, out);
}